// Round 20
// baseline (1953.755 us; speedup 1.0000x reference)
//
#include <hip/hip_runtime.h>
#include <hip/hip_bf16.h>
#include <cstdint>
#include <cstddef>

typedef unsigned short u16;
typedef _Float16 f16;
typedef f16 f16x8 __attribute__((ext_vector_type(8)));
typedef float f32x4 __attribute__((ext_vector_type(4)));

static __device__ __forceinline__ u16 f2h(float f) {
    f16 h = (f16)f;
    return *reinterpret_cast<u16*>(&h);
}
static __device__ __forceinline__ float h2f(u16 u) {
    f16 h = *reinterpret_cast<f16*>(&u);
    return (float)h;
}

// async global->LDS, 16B per lane; LDS dest = wave-uniform base + lane*16
#define GLL(g, l) __builtin_amdgcn_global_load_lds(                    \
    (const __attribute__((address_space(1))) void*)(g),                \
    (__attribute__((address_space(3))) void*)(l), 16, 0, 0)

// bijective XCD swizzle (all grids % 8 == 0)
static __device__ __forceinline__ int xcd_swz(int fid, int nwg) {
    const int q = nwg >> 3;
    return (fid & 7) * q + (fid >> 3);
}

#define TDIR (32ull * 512 * 1024)

// stage a 128x32 u16 tile into LDS, XOR-swizzled via the GLOBAL source col
// (GLL dest linear, rule #21): LDS(row, c) = src[row][c ^ ((row&3)<<3)] (u16 units)
static __device__ __forceinline__ void stage_tile(const u16* __restrict__ src, int ld,
                                                  u16* lds, int wave, int lane) {
    const int r = lane >> 2;                                 // 0..15
    const int c = ((lane & 3) << 3) ^ ((r & 3) << 3);        // u16 units, swizzled
    const u16* g0 = src + (size_t)(wave * 32 + r) * ld + c;
    GLL(g0, lds + wave * 1024);
    GLL(g0 + (size_t)16 * ld, lds + wave * 1024 + 512);      // row+16: same (r&3)
}

// stage a 64x32 u16 tile (1 GLL/thread, 256 threads), same XOR swizzle
static __device__ __forceinline__ void stage_tile64(const u16* __restrict__ src, int ld,
                                                    u16* lds, int t) {
    const int r = t >> 2;                                    // 0..63
    const int c = ((t & 3) << 3) ^ ((r & 3) << 3);
    GLL(src + (size_t)r * ld + c, lds + ((t >> 6) << 9));
}

// read this wave's fragments for one K=32 step (swizzled col)
static __device__ __forceinline__ void ds_read_frags(const u16* lA, const u16* lB,
                                                     int wq_r, int wq_c, int lr, int ce,
                                                     f16x8 a[4], f16x8 b[4]) {
    #pragma unroll
    for (int i = 0; i < 4; ++i)
        a[i] = *reinterpret_cast<const f16x8*>(&lA[(wq_r + i * 16 + lr) * 32 + ce]);
    #pragma unroll
    for (int j = 0; j < 4; ++j)
        b[j] = *reinterpret_cast<const f16x8*>(&lB[(wq_c + j * 16 + lr) * 32 + ce]);
}

static __device__ __forceinline__ void mfma16(const f16x8 a[4], const f16x8 b[4],
                                              f32x4 acc[4][4]) {
    #pragma unroll
    for (int i = 0; i < 4; ++i)
        #pragma unroll
        for (int j = 0; j < 4; ++j)
            acc[i][j] = __builtin_amdgcn_mfma_f32_16x16x32_f16(a[i], b[j], acc[i][j], 0, 0, 0);
}

#define WAIT_LGKM0 { asm volatile("s_waitcnt lgkmcnt(0)" ::: "memory"); \
                     __builtin_amdgcn_sched_barrier(0); }
#define WAIT_VM(n) { asm volatile("s_waitcnt vmcnt(" #n ")" ::: "memory"); \
                     __builtin_amdgcn_sched_barrier(0); }

// ---- 128x128 core, 2-buffer read-to-regs counted pipeline (T14+T4) ----
static __device__ __forceinline__ void gemm128p(const u16* __restrict__ a1, int lda1, int ka1,
                                                const u16* __restrict__ a2, int lda2,
                                                const u16* __restrict__ bt, int ldb,
                                                int K, int m0, int n0,
                                                u16* sA, u16* sB, f32x4 acc[4][4])
{
    const int t = threadIdx.x, lane = t & 63, wave = t >> 6;
    const int lr = lane & 15, lk = (lane >> 4) << 3;
    const int ce = lk ^ ((lr & 3) << 3);
    const int wq_r = (wave >> 1) << 6, wq_c = (wave & 1) << 6;
    const int nt = K >> 5;

    auto stA = [&](int kt, u16* dst) {
        const int k0 = kt << 5;
        const u16* s; int ld;
        if (k0 < ka1) { s = a1 + (size_t)m0 * lda1 + k0;         ld = lda1; }
        else          { s = a2 + (size_t)m0 * lda2 + (k0 - ka1); ld = lda2; }
        stage_tile(s, ld, dst, wave, lane);
    };
    auto stB = [&](int kt, u16* dst) {
        stage_tile(bt + (size_t)n0 * ldb + (kt << 5), ldb, dst, wave, lane);
    };

    stA(0, sA);        stB(0, sB);
    stA(1, sA + 4096); stB(1, sB + 4096);
    WAIT_VM(4)
    __builtin_amdgcn_s_barrier();

    for (int ti = 0; ti < nt; ti += 2) {
        {   // buffer X (ktile ti)
            f16x8 a[4], b[4];
            ds_read_frags(sA, sB, wq_r, wq_c, lr, ce, a, b);
            WAIT_LGKM0
            __builtin_amdgcn_s_barrier();
            const bool pre = (ti + 2) < nt;
            if (pre) { stA(ti + 2, sA); stB(ti + 2, sB); }
            mfma16(a, b, acc);
            if (pre) { WAIT_VM(4) } else { WAIT_VM(0) }
            __builtin_amdgcn_s_barrier();
        }
        {   // buffer Y (ktile ti+1)
            f16x8 a[4], b[4];
            ds_read_frags(sA + 4096, sB + 4096, wq_r, wq_c, lr, ce, a, b);
            WAIT_LGKM0
            __builtin_amdgcn_s_barrier();
            const bool pre = (ti + 3) < nt;
            if (pre) { stA(ti + 3, sA + 4096); stB(ti + 3, sB + 4096); }
            mfma16(a, b, acc);
            if (pre) { WAIT_VM(4) } else { WAIT_VM(0) }
            __builtin_amdgcn_s_barrier();
        }
    }
}

// ---- 128x64 core, same counted pipeline (3 loads/ktile), for 1-block/CU kernels ----
static __device__ __forceinline__ void gemm128p64(const u16* __restrict__ a1, int lda1, int ka1,
                                                  const u16* __restrict__ a2, int lda2,
                                                  const u16* __restrict__ bt, int ldb,
                                                  int K, int m0, int n0,
                                                  u16* sA, u16* sB, f32x4 acc[2][4])
{
    const int t = threadIdx.x, lane = t & 63, wave = t >> 6;
    const int lr = lane & 15, lk = (lane >> 4) << 3;
    const int ce = lk ^ ((lr & 3) << 3);
    const int wq_r = wave << 5;
    const int nt = K >> 5;

    auto stA = [&](int kt, u16* dst) {
        const int k0 = kt << 5;
        const u16* s; int ld;
        if (k0 < ka1) { s = a1 + (size_t)m0 * lda1 + k0;         ld = lda1; }
        else          { s = a2 + (size_t)m0 * lda2 + (k0 - ka1); ld = lda2; }
        stage_tile(s, ld, dst, wave, lane);
    };
    auto stB = [&](int kt, u16* dst) {
        stage_tile64(bt + (size_t)n0 * ldb + (kt << 5), ldb, dst, t);
    };
    auto rdfr = [&](const u16* lA, const u16* lB, f16x8 a[2], f16x8 b[4]) {
        #pragma unroll
        for (int i = 0; i < 2; ++i)
            a[i] = *reinterpret_cast<const f16x8*>(&lA[(wq_r + i * 16 + lr) * 32 + ce]);
        #pragma unroll
        for (int j = 0; j < 4; ++j)
            b[j] = *reinterpret_cast<const f16x8*>(&lB[(j * 16 + lr) * 32 + ce]);
    };
    auto mm = [&](const f16x8 a[2], const f16x8 b[4]) {
        #pragma unroll
        for (int i = 0; i < 2; ++i)
            #pragma unroll
            for (int j = 0; j < 4; ++j)
                acc[i][j] = __builtin_amdgcn_mfma_f32_16x16x32_f16(a[i], b[j], acc[i][j], 0, 0, 0);
    };

    stA(0, sA);        stB(0, sB);
    stA(1, sA + 4096); stB(1, sB + 2048);
    WAIT_VM(3)
    __builtin_amdgcn_s_barrier();

    for (int ti = 0; ti < nt; ti += 2) {
        {
            f16x8 a[2], b[4];
            rdfr(sA, sB, a, b);
            WAIT_LGKM0
            __builtin_amdgcn_s_barrier();
            const bool pre = (ti + 2) < nt;
            if (pre) { stA(ti + 2, sA); stB(ti + 2, sB); }
            mm(a, b);
            if (pre) { WAIT_VM(3) } else { WAIT_VM(0) }
            __builtin_amdgcn_s_barrier();
        }
        {
            f16x8 a[2], b[4];
            rdfr(sA + 4096, sB + 2048, a, b);
            WAIT_LGKM0
            __builtin_amdgcn_s_barrier();
            const bool pre = (ti + 3) < nt;
            if (pre) { stA(ti + 3, sA + 4096); stB(ti + 3, sB + 2048); }
            mm(a, b);
            if (pre) { WAIT_VM(3) } else { WAIT_VM(0) }
            __builtin_amdgcn_s_barrier();
        }
    }
}

#define EPI                                         \
    const int lane = threadIdx.x & 63;              \
    const int wave = threadIdx.x >> 6;              \
    const int wq_r = (wave >> 1) << 6;              \
    const int wq_c = (wave & 1) << 6;               \
    const int lr = lane & 15;                       \
    const int l4 = (lane >> 4) << 2;

#define EPI64                                       \
    const int lane = threadIdx.x & 63;              \
    const int wave = threadIdx.x >> 6;              \
    const int wq_r = wave << 5;                     \
    const int lr = lane & 15;                       \
    const int l4 = (lane >> 4) << 2;

// mega-projection: C[8192 x 4096] = P @ Wio^T ; col = dir*2048 + e*512 + h
// write transposed: T[dir][b][h][e*256+m].  K=256 at step 0 (prop = [ann|0]).
// launch_bounds(256,5): LDS 32KB x 5 = 160KB/CU exactly; VGPR 60 < 512/5.
__global__ __launch_bounds__(256, 5) void k_proj(const u16* __restrict__ P,
                                                 const u16* __restrict__ Wio,
                                                 const float* __restrict__ b_in,
                                                 const float* __restrict__ b_out,
                                                 u16* __restrict__ T, int K)
{
    __shared__ u16 sA[2 * 4096], sB[2 * 4096];
    const int fid = xcd_swz(blockIdx.x, gridDim.x);
    const int reg = fid >> 8;                // 0..7 (one per XCD)
    const int inner = fid & 255;
    const int m = ((reg >> 1) << 4) | (inner & 15);   // 0..63
    const int n = ((reg & 1) << 4) | (inner >> 4);    // 0..31
    const int m0 = m << 7, n0 = n << 7;
    f32x4 acc[4][4] = {};
    gemm128p(P, 512, 512, P, 512, Wio, 512, K, m0, n0, sA, sB, acc);
    EPI
    #pragma unroll
    for (int i = 0; i < 4; ++i) {
        const int row = m0 + wq_r + i * 16 + l4;
        const int b = row >> 8, mm = row & 255;
        #pragma unroll
        for (int j = 0; j < 4; ++j) {
            const int col = n0 + wq_c + j * 16 + lr;
            const int dir = col >> 11, eh = col & 2047;
            const float bia = (dir ? b_out : b_in)[eh];
            const int e = eh >> 9, hh = eh & 511;
            ushort4 w4;
            w4.x = f2h(acc[i][j][0] + bia);
            w4.y = f2h(acc[i][j][1] + bia);
            w4.z = f2h(acc[i][j][2] + bia);
            w4.w = f2h(acc[i][j][3] + bia);
            *reinterpret_cast<ushort4*>(&T[(size_t)dir * TDIR + (size_t)b * 512 * 1024
                                           + (size_t)hh * 1024 + e * 256 + mm]) = w4;
        }
    }
}

// adjacency: per (b,dir): C[256x512] = A16[b][:, dir*1024:+1024] @ T[dir][b]^T
__global__ __launch_bounds__(256, 5) void k_amat(const u16* __restrict__ A16,
                                                 const u16* __restrict__ T,
                                                 u16* __restrict__ acat)
{
    __shared__ u16 sA[2 * 4096], sB[2 * 4096];
    const int fid = xcd_swz(blockIdx.x, gridDim.x);
    const int n = fid & 3, m = (fid >> 2) & 1, bd = fid >> 3;
    const int b = bd >> 1, dir = bd & 1;
    const int m0 = m << 7, n0 = n << 7;
    const u16* A1 = A16 + (size_t)b * 256 * 2048 + dir * 1024;
    const u16* Bt = T + (size_t)dir * TDIR + (size_t)b * 512 * 1024;
    f32x4 acc[4][4] = {};
    gemm128p(A1, 2048, 1024, A1, 2048, Bt, 1024, 1024, m0, n0, sA, sB, acc);
    EPI
    #pragma unroll
    for (int i = 0; i < 4; ++i) {
        const int row = m0 + wq_r + i * 16 + l4;
        #pragma unroll
        for (int j = 0; j < 4; ++j) {
            const int col = n0 + wq_c + j * 16 + lr;
            #pragma unroll
            for (int v = 0; v < 4; ++v)
                acat[((size_t)b * 256 + row + v) * 1024 + dir * 512 + col] = f2h(acc[i][j][v]);
        }
    }
}

// gates: X[8192 x 1536] = [acat | P] @ Wrzh^T (h-block zero-padded over P rows).
// K-trims: h-blocks (n0>=1024) K=1024; step 0 r/z blocks Krz=1280 (P cols 256-511 zero).
__global__ __launch_bounds__(256, 5) void k_gates(const u16* __restrict__ acat,
                                                  const u16* __restrict__ P,
                                                  const u16* __restrict__ Wrzh,
                                                  const float* __restrict__ br,
                                                  const float* __restrict__ bz,
                                                  u16* __restrict__ rp,
                                                  u16* __restrict__ z16,
                                                  u16* __restrict__ hp16,
                                                  int Krz)
{
    __shared__ u16 sA[2 * 4096], sB[2 * 4096];
    const int fid = xcd_swz(blockIdx.x, gridDim.x);
    const int n = fid % 12, m = fid / 12;
    const int m0 = m << 7, n0 = n << 7;
    const int K = (n0 >= 1024) ? 1024 : Krz;
    f32x4 acc[4][4] = {};
    gemm128p(acat, 1024, 1024, P, 512, Wrzh, 1536, K, m0, n0, sA, sB, acc);
    EPI
    #pragma unroll
    for (int i = 0; i < 4; ++i) {
        const int row = m0 + wq_r + i * 16 + l4;
        #pragma unroll
        for (int j = 0; j < 4; ++j) {
            const int col = n0 + wq_c + j * 16 + lr;
            if (col < 512) {
                const float bia = br[col];
                #pragma unroll
                for (int v = 0; v < 4; ++v) {
                    const float s = 1.0f / (1.0f + __expf(-(acc[i][j][v] + bia)));
                    const size_t idx = (size_t)(row + v) * 512 + col;
                    rp[idx] = f2h(s * h2f(P[idx]));
                }
            } else if (col < 1024) {
                const float bia = bz[col - 512];
                #pragma unroll
                for (int v = 0; v < 4; ++v)
                    z16[(size_t)(row + v) * 512 + (col - 512)] =
                        f2h(1.0f / (1.0f + __expf(-(acc[i][j][v] + bia))));
            } else {
                #pragma unroll
                for (int v = 0; v < 4; ++v)
                    hp16[(size_t)(row + v) * 512 + (col - 1024)] = f2h(acc[i][j][v]);
            }
        }
    }
}

// h/update: Y = rp @ WhP^T ; h = tanh(hp + Y + bh) ; P = (1-z)P + z h
// 128x64 tiles. K=256 at step 0 (rp cols 256-511 zero).
__global__ __launch_bounds__(256, 4) void k_hup(const u16* __restrict__ rp,
                                                const u16* __restrict__ WhP,
                                                const float* __restrict__ bh,
                                                const u16* __restrict__ z16,
                                                const u16* __restrict__ hp16,
                                                u16* __restrict__ P, int K)
{
    __shared__ u16 sA[2 * 4096], sB[2 * 2048];
    const int fid = xcd_swz(blockIdx.x, gridDim.x);
    const int n = fid & 7, m = fid >> 3;
    const int m0 = m << 7, n0 = n << 6;
    f32x4 acc[2][4] = {};
    gemm128p64(rp, 512, 512, rp, 512, WhP, 512, K, m0, n0, sA, sB, acc);
    EPI64
    #pragma unroll
    for (int i = 0; i < 2; ++i) {
        const int row = m0 + wq_r + i * 16 + l4;
        #pragma unroll
        for (int j = 0; j < 4; ++j) {
            const int col = n0 + j * 16 + lr;
            const float bia = bh[col];
            #pragma unroll
            for (int v = 0; v < 4; ++v) {
                const size_t idx = (size_t)(row + v) * 512 + col;
                const float hh = tanhf(h2f(hp16[idx]) + acc[i][j][v] + bia);
                const float zz = h2f(z16[idx]);
                const float pn = (1.0f - zz) * h2f(P[idx]) + zz * hh;
                P[idx] = f2h(pn);
            }
        }
    }
}

// final: out = tanh([P | ann] @ Wj^T + bo) (f32), 128x64 tiles, grid 512
__global__ __launch_bounds__(256, 4) void k_final(const u16* __restrict__ P,
                                                  const u16* __restrict__ annf,
                                                  const u16* __restrict__ Wj,
                                                  const float* __restrict__ bo,
                                                  float* __restrict__ out)
{
    __shared__ u16 sA[2 * 4096], sB[2 * 2048];
    const int fid = xcd_swz(blockIdx.x, gridDim.x);
    const int n = fid & 7, m = fid >> 3;
    const int m0 = m << 7, n0 = n << 6;
    f32x4 acc[2][4] = {};
    gemm128p64(P, 512, 512, annf, 256, Wj, 768, 768, m0, n0, sA, sB, acc);
    EPI64
    #pragma unroll
    for (int i = 0; i < 2; ++i) {
        const int row = m0 + wq_r + i * 16 + l4;
        #pragma unroll
        for (int j = 0; j < 4; ++j) {
            const int col = n0 + j * 16 + lr;
            const float bia = bo[col];
            #pragma unroll
            for (int v = 0; v < 4; ++v)
                out[(size_t)(row + v) * 512 + col] = tanhf(acc[i][j][v] + bia);
        }
    }
}

// ---- fused setup: block-segmented. Blocks [0,16384): gather; [16384,24576):
// A f32->f16; [24576, 24576+1248): LDS-tiled 64x64 weight transposes ----
#define BGATH 16384
#define BCVTA 8192
#define TT_WIO  512
#define TT_WR   192
#define TT_WZ   192
#define TT_WH   128
#define TT_Z0   64
#define TT_WHP  64
#define TT_WJ   96
// total tiles = 1248 ; grid = 16384 + 8192 + 1248 = 25824
__global__ void s_setup(const int* __restrict__ ann, const float* __restrict__ emb,
                        const float* __restrict__ A,
                        const float* __restrict__ Wi, const float* __restrict__ Wo,
                        const float* __restrict__ Wr, const float* __restrict__ Wz,
                        const float* __restrict__ Wh, const float* __restrict__ Wj,
                        u16* __restrict__ P, u16* __restrict__ annf,
                        u16* __restrict__ A16,
                        u16* __restrict__ dWio, u16* __restrict__ dWrzh,
                        u16* __restrict__ dWhP, u16* __restrict__ dWj)
{
    const int bid = blockIdx.x, tid = threadIdx.x;
    if (bid < BGATH) {
        const int gid = bid * 256 + tid;             // < 8192*512
        const int row = gid >> 9, d = gid & 511;
        float v = 0.0f;
        if (d < 256) v = emb[(size_t)ann[row] * 256 + d];
        const u16 h = f2h(v);
        P[gid] = h;
        if (d < 256) annf[((size_t)row << 8) + d] = h;
        return;
    }
    if (bid < BGATH + BCVTA) {
        const size_t base = ((size_t)(bid - BGATH) * 256 + tid) * 8;   // < 8192*2048
        float4 f0 = *reinterpret_cast<const float4*>(A + base);
        float4 f1 = *reinterpret_cast<const float4*>(A + base + 4);
        ushort4 p0 = { f2h(f0.x), f2h(f0.y), f2h(f0.z), f2h(f0.w) };
        ushort4 p1 = { f2h(f1.x), f2h(f1.y), f2h(f1.z), f2h(f1.w) };
        *reinterpret_cast<ushort4*>(A16 + base)     = p0;
        *reinterpret_cast<ushort4*>(A16 + base + 4) = p1;
        return;
    }
    // ---- transpose tiles ----
    int tt = bid - (BGATH + BCVTA);
    const float* src = nullptr;       // [*][512] row-major
    u16* dst = nullptr;               // dst[n0+i][k0+j] = src[k0+j][n0+i]
    int ldk = 0, n0 = 0, k0 = 0;
    bool zero = false;
    if (tt < TT_WIO) {
        const int sub = tt >> 6, rem = tt & 63;
        const int dir = sub >> 2, e = sub & 3;
        src = (dir ? Wo : Wi) + (size_t)e * 262144;
        dst = dWio + (size_t)(dir * 2048 + e * 512) * 512;
        ldk = 512; n0 = ((rem >> 3) & 7) << 6; k0 = (rem & 7) << 6;
    } else if ((tt -= TT_WIO) < TT_WR) {
        src = Wr; dst = dWrzh; ldk = 1536;
        n0 = (tt / 24) << 6; k0 = (tt % 24) << 6;
    } else if ((tt -= TT_WR) < TT_WZ) {
        src = Wz; dst = dWrzh + 512 * 1536; ldk = 1536;
        n0 = (tt / 24) << 6; k0 = (tt % 24) << 6;
    } else if ((tt -= TT_WZ) < TT_WH) {
        src = Wh; dst = dWrzh + 1024 * 1536; ldk = 1536;
        n0 = (tt >> 4) << 6; k0 = (tt & 15) << 6;        // k < 1024
    } else if ((tt -= TT_WH) < TT_Z0) {
        dst = dWrzh + 1024 * 1536; ldk = 1536;
        n0 = (tt >> 3) << 6; k0 = 1024 + ((tt & 7) << 6);
        zero = true;
    } else if ((tt -= TT_Z0) < TT_WHP) {
        src = Wh + 1024 * 512; dst = dWhP; ldk = 512;
        n0 = (tt >> 3) << 6; k0 = (tt & 7) << 6;
    } else {
        tt -= TT_WHP;                                    // < TT_WJ
        src = Wj; dst = dWj; ldk = 768;
        n0 = (tt / 12) << 6; k0 = (tt % 12) << 6;
    }

    if (zero) {
        const int jj4 = (tid & 15) << 2;
        #pragma unroll
        for (int p = 0; p < 4; ++p) {
            const int i = (tid >> 4) + p * 16;
            ushort4 zz = { 0, 0, 0, 0 };
            *reinterpret_cast<ushort4*>(&dst[(size_t)(n0 + i) * ldk + k0 + jj4]) = zz;
        }
        return;
    }

    __shared__ float lds[64][65];                        // +1 pad
    {
        const int jj = tid >> 4, i4 = (tid & 15) << 2;
        #pragma unroll
        for (int p = 0; p < 4; ++p) {
            const int j = jj + p * 16;
            float4 f = *reinterpret_cast<const float4*>(src + (size_t)(k0 + j) * 512 + n0 + i4);
            lds[j][i4] = f.x; lds[j][i4 + 1] = f.y; lds[j][i4 + 2] = f.z; lds[j][i4 + 3] = f.w;
        }
    }
    __syncthreads();
    {
        const int j4 = (tid & 15) << 2;
        #pragma unroll
        for (int p = 0; p < 4; ++p) {
            const int i = (tid >> 4) + p * 16;
            ushort4 w;
            w.x = f2h(lds[j4][i]);
            w.y = f2h(lds[j4 + 1][i]);
            w.z = f2h(lds[j4 + 2][i]);
            w.w = f2h(lds[j4 + 3][i]);
            *reinterpret_cast<ushort4*>(&dst[(size_t)(n0 + i) * ldk + k0 + j4]) = w;
        }
    }
}

extern "C" void kernel_launch(void* const* d_in, const int* in_sizes, int n_in,
                              void* d_out, int out_size, void* d_ws, size_t ws_size,
                              hipStream_t stream) {
    const int*   ann   = (const int*)d_in[0];
    const float* A     = (const float*)d_in[1];
    const float* emb   = (const float*)d_in[2];
    const float* W_in  = (const float*)d_in[3];
    const float* b_in  = (const float*)d_in[4];
    const float* W_out = (const float*)d_in[5];
    const float* b_out = (const float*)d_in[6];
    const float* Wr    = (const float*)d_in[7];
    const float* br    = (const float*)d_in[8];
    const float* Wz    = (const float*)d_in[9];
    const float* bz    = (const float*)d_in[10];
    const float* Wh    = (const float*)d_in[11];
    const float* bh    = (const float*)d_in[12];
    const float* Wo    = (const float*)d_in[13];
    const float* bo    = (const float*)d_in[14];
    float* out = (float*)d_out;

    char* ws = (char*)d_ws;
    size_t off = 0;
    auto alloc = [&](size_t bytes) -> void* {
        void* p = ws + off;
        off = (off + bytes + 255) & ~(size_t)255;
        return p;
    };
    u16* z16   = (u16*)alloc(8192ull * 512 * 2);       // 8 MB
    u16* hp16  = (u16*)alloc(8192ull * 512 * 2);       // 8 MB
    u16* P     = (u16*)alloc(8192ull * 512 * 2);       // 8 MB
    u16* rp    = (u16*)alloc(8192ull * 512 * 2);       // 8 MB
    u16* annf  = (u16*)alloc(8192ull * 256 * 2);       // 4 MB
    u16* acat  = (u16*)alloc(8192ull * 1024 * 2);      // 16 MB
    u16* A16   = (u16*)alloc(8192ull * 2048 * 2);      // 32 MB
    u16* T     = (u16*)alloc(2 * TDIR * 2);            // 64 MB
    u16* WioT  = (u16*)alloc(4096ull * 512 * 2);       // 4 MB
    u16* WrzhT = (u16*)alloc(1536ull * 1536 * 2);      // 4.7 MB
    u16* WhPT  = (u16*)alloc(512ull * 512 * 2);        // 0.5 MB
    u16* WjT   = (u16*)alloc(512ull * 768 * 2);        // 0.8 MB
    // total ~158 MB

    s_setup<<<25824, 256, 0, stream>>>(ann, emb, A, W_in, W_out, Wr, Wz, Wh, Wo,
                                       P, annf, A16, WioT, WrzhT, WhPT, WjT);

    for (int s = 0; s < 5; ++s) {
        k_proj<<<2048, 256, 0, stream>>>(P, WioT, b_in, b_out, T, s == 0 ? 256 : 512);
        k_amat<<<512, 256, 0, stream>>>(A16, T, acat);
        k_gates<<<768, 256, 0, stream>>>(acat, P, WrzhT, br, bz, rp, z16, hp16,
                                         s == 0 ? 1280 : 1536);
        k_hup<<<512, 256, 0, stream>>>(rp, WhPT, bh, z16, hp16, P, s == 0 ? 256 : 512);
    }
    k_final<<<512, 256, 0, stream>>>(P, annf, WjT, bo, out);
}

// Round 21
// 782.014 us; speedup vs baseline: 2.4984x; 2.4984x over previous
//
#include <hip/hip_runtime.h>
#include <hip/hip_bf16.h>
#include <cstdint>
#include <cstddef>

typedef unsigned short u16;
typedef _Float16 f16;
typedef f16 f16x8 __attribute__((ext_vector_type(8)));
typedef float f32x4 __attribute__((ext_vector_type(4)));

static __device__ __forceinline__ u16 f2h(float f) {
    f16 h = (f16)f;
    return *reinterpret_cast<u16*>(&h);
}
static __device__ __forceinline__ float h2f(u16 u) {
    f16 h = *reinterpret_cast<f16*>(&u);
    return (float)h;
}

// async global->LDS, 16B per lane; LDS dest = wave-uniform base + lane*16
#define GLL(g, l) __builtin_amdgcn_global_load_lds(                    \
    (const __attribute__((address_space(1))) void*)(g),                \
    (__attribute__((address_space(3))) void*)(l), 16, 0, 0)

// bijective XCD swizzle (all grids % 8 == 0)
static __device__ __forceinline__ int xcd_swz(int fid, int nwg) {
    const int q = nwg >> 3;
    return (fid & 7) * q + (fid >> 3);
}

#define TDIR (32ull * 512 * 1024)

// stage a 128x32 u16 tile into LDS, XOR-swizzled via the GLOBAL source col
// (GLL dest linear, rule #21): LDS(row, c) = src[row][c ^ ((row&3)<<3)] (u16 units)
static __device__ __forceinline__ void stage_tile(const u16* __restrict__ src, int ld,
                                                  u16* lds, int wave, int lane) {
    const int r = lane >> 2;                                 // 0..15
    const int c = ((lane & 3) << 3) ^ ((r & 3) << 3);        // u16 units, swizzled
    const u16* g0 = src + (size_t)(wave * 32 + r) * ld + c;
    GLL(g0, lds + wave * 1024);
    GLL(g0 + (size_t)16 * ld, lds + wave * 1024 + 512);      // row+16: same (r&3)
}

// stage a 64x32 u16 tile (1 GLL/thread, 256 threads), same XOR swizzle
static __device__ __forceinline__ void stage_tile64(const u16* __restrict__ src, int ld,
                                                    u16* lds, int t) {
    const int r = t >> 2;                                    // 0..63
    const int c = ((t & 3) << 3) ^ ((r & 3) << 3);
    GLL(src + (size_t)r * ld + c, lds + ((t >> 6) << 9));
}

// read this wave's fragments for one K=32 step (swizzled col)
static __device__ __forceinline__ void ds_read_frags(const u16* lA, const u16* lB,
                                                     int wq_r, int wq_c, int lr, int ce,
                                                     f16x8 a[4], f16x8 b[4]) {
    #pragma unroll
    for (int i = 0; i < 4; ++i)
        a[i] = *reinterpret_cast<const f16x8*>(&lA[(wq_r + i * 16 + lr) * 32 + ce]);
    #pragma unroll
    for (int j = 0; j < 4; ++j)
        b[j] = *reinterpret_cast<const f16x8*>(&lB[(wq_c + j * 16 + lr) * 32 + ce]);
}

static __device__ __forceinline__ void mfma16(const f16x8 a[4], const f16x8 b[4],
                                              f32x4 acc[4][4]) {
    #pragma unroll
    for (int i = 0; i < 4; ++i)
        #pragma unroll
        for (int j = 0; j < 4; ++j)
            acc[i][j] = __builtin_amdgcn_mfma_f32_16x16x32_f16(a[i], b[j], acc[i][j], 0, 0, 0);
}

#define WAIT_LGKM0 { asm volatile("s_waitcnt lgkmcnt(0)" ::: "memory"); \
                     __builtin_amdgcn_sched_barrier(0); }
#define WAIT_VM(n) { asm volatile("s_waitcnt vmcnt(" #n ")" ::: "memory"); \
                     __builtin_amdgcn_sched_barrier(0); }

// ---- 128x128 core, 2-buffer read-to-regs counted pipeline (T14+T4) ----
static __device__ __forceinline__ void gemm128p(const u16* __restrict__ a1, int lda1, int ka1,
                                                const u16* __restrict__ a2, int lda2,
                                                const u16* __restrict__ bt, int ldb,
                                                int K, int m0, int n0,
                                                u16* sA, u16* sB, f32x4 acc[4][4])
{
    const int t = threadIdx.x, lane = t & 63, wave = t >> 6;
    const int lr = lane & 15, lk = (lane >> 4) << 3;
    const int ce = lk ^ ((lr & 3) << 3);
    const int wq_r = (wave >> 1) << 6, wq_c = (wave & 1) << 6;
    const int nt = K >> 5;

    auto stA = [&](int kt, u16* dst) {
        const int k0 = kt << 5;
        const u16* s; int ld;
        if (k0 < ka1) { s = a1 + (size_t)m0 * lda1 + k0;         ld = lda1; }
        else          { s = a2 + (size_t)m0 * lda2 + (k0 - ka1); ld = lda2; }
        stage_tile(s, ld, dst, wave, lane);
    };
    auto stB = [&](int kt, u16* dst) {
        stage_tile(bt + (size_t)n0 * ldb + (kt << 5), ldb, dst, wave, lane);
    };

    stA(0, sA);        stB(0, sB);
    stA(1, sA + 4096); stB(1, sB + 4096);
    WAIT_VM(4)
    __builtin_amdgcn_s_barrier();

    for (int ti = 0; ti < nt; ti += 2) {
        {   // buffer X (ktile ti)
            f16x8 a[4], b[4];
            ds_read_frags(sA, sB, wq_r, wq_c, lr, ce, a, b);
            WAIT_LGKM0
            __builtin_amdgcn_s_barrier();
            const bool pre = (ti + 2) < nt;
            if (pre) { stA(ti + 2, sA); stB(ti + 2, sB); }
            mfma16(a, b, acc);
            if (pre) { WAIT_VM(4) } else { WAIT_VM(0) }
            __builtin_amdgcn_s_barrier();
        }
        {   // buffer Y (ktile ti+1)
            f16x8 a[4], b[4];
            ds_read_frags(sA + 4096, sB + 4096, wq_r, wq_c, lr, ce, a, b);
            WAIT_LGKM0
            __builtin_amdgcn_s_barrier();
            const bool pre = (ti + 3) < nt;
            if (pre) { stA(ti + 3, sA + 4096); stB(ti + 3, sB + 4096); }
            mfma16(a, b, acc);
            if (pre) { WAIT_VM(4) } else { WAIT_VM(0) }
            __builtin_amdgcn_s_barrier();
        }
    }
}

// ---- 128x64 core, same counted pipeline (3 loads/ktile), for 1-block/CU kernels ----
static __device__ __forceinline__ void gemm128p64(const u16* __restrict__ a1, int lda1, int ka1,
                                                  const u16* __restrict__ a2, int lda2,
                                                  const u16* __restrict__ bt, int ldb,
                                                  int K, int m0, int n0,
                                                  u16* sA, u16* sB, f32x4 acc[2][4])
{
    const int t = threadIdx.x, lane = t & 63, wave = t >> 6;
    const int lr = lane & 15, lk = (lane >> 4) << 3;
    const int ce = lk ^ ((lr & 3) << 3);
    const int wq_r = wave << 5;
    const int nt = K >> 5;

    auto stA = [&](int kt, u16* dst) {
        const int k0 = kt << 5;
        const u16* s; int ld;
        if (k0 < ka1) { s = a1 + (size_t)m0 * lda1 + k0;         ld = lda1; }
        else          { s = a2 + (size_t)m0 * lda2 + (k0 - ka1); ld = lda2; }
        stage_tile(s, ld, dst, wave, lane);
    };
    auto stB = [&](int kt, u16* dst) {
        stage_tile64(bt + (size_t)n0 * ldb + (kt << 5), ldb, dst, t);
    };
    auto rdfr = [&](const u16* lA, const u16* lB, f16x8 a[2], f16x8 b[4]) {
        #pragma unroll
        for (int i = 0; i < 2; ++i)
            a[i] = *reinterpret_cast<const f16x8*>(&lA[(wq_r + i * 16 + lr) * 32 + ce]);
        #pragma unroll
        for (int j = 0; j < 4; ++j)
            b[j] = *reinterpret_cast<const f16x8*>(&lB[(j * 16 + lr) * 32 + ce]);
    };
    auto mm = [&](const f16x8 a[2], const f16x8 b[4]) {
        #pragma unroll
        for (int i = 0; i < 2; ++i)
            #pragma unroll
            for (int j = 0; j < 4; ++j)
                acc[i][j] = __builtin_amdgcn_mfma_f32_16x16x32_f16(a[i], b[j], acc[i][j], 0, 0, 0);
    };

    stA(0, sA);        stB(0, sB);
    stA(1, sA + 4096); stB(1, sB + 2048);
    WAIT_VM(3)
    __builtin_amdgcn_s_barrier();

    for (int ti = 0; ti < nt; ti += 2) {
        {
            f16x8 a[2], b[4];
            rdfr(sA, sB, a, b);
            WAIT_LGKM0
            __builtin_amdgcn_s_barrier();
            const bool pre = (ti + 2) < nt;
            if (pre) { stA(ti + 2, sA); stB(ti + 2, sB); }
            mm(a, b);
            if (pre) { WAIT_VM(3) } else { WAIT_VM(0) }
            __builtin_amdgcn_s_barrier();
        }
        {
            f16x8 a[2], b[4];
            rdfr(sA + 4096, sB + 2048, a, b);
            WAIT_LGKM0
            __builtin_amdgcn_s_barrier();
            const bool pre = (ti + 3) < nt;
            if (pre) { stA(ti + 3, sA + 4096); stB(ti + 3, sB + 2048); }
            mm(a, b);
            if (pre) { WAIT_VM(3) } else { WAIT_VM(0) }
            __builtin_amdgcn_s_barrier();
        }
    }
}

#define EPI                                         \
    const int lane = threadIdx.x & 63;              \
    const int wave = threadIdx.x >> 6;              \
    const int wq_r = (wave >> 1) << 6;              \
    const int wq_c = (wave & 1) << 6;               \
    const int lr = lane & 15;                       \
    const int l4 = (lane >> 4) << 2;

#define EPI64                                       \
    const int lane = threadIdx.x & 63;              \
    const int wave = threadIdx.x >> 6;              \
    const int wq_r = wave << 5;                     \
    const int lr = lane & 15;                       \
    const int l4 = (lane >> 4) << 2;

// mega-projection: C[8192 x 4096] = P @ Wio^T ; col = dir*2048 + e*512 + h
// write transposed: T[dir][b][h][e*256+m].  K=256 at step 0 (prop = [ann|0]).
// 2D XCD tiling: per-XCD 16m x 16n tile -> working set 4MB = L2.
// launch_bounds(256,4): bound of 5 spills (r20: VGPR 60->48, scratch traffic 6x).
__global__ __launch_bounds__(256, 4) void k_proj(const u16* __restrict__ P,
                                                 const u16* __restrict__ Wio,
                                                 const float* __restrict__ b_in,
                                                 const float* __restrict__ b_out,
                                                 u16* __restrict__ T, int K)
{
    __shared__ u16 sA[2 * 4096], sB[2 * 4096];
    const int fid = xcd_swz(blockIdx.x, gridDim.x);
    const int reg = fid >> 8;                // 0..7 (one per XCD)
    const int inner = fid & 255;
    const int m = ((reg >> 1) << 4) | (inner & 15);   // 0..63
    const int n = ((reg & 1) << 4) | (inner >> 4);    // 0..31
    const int m0 = m << 7, n0 = n << 7;
    f32x4 acc[4][4] = {};
    gemm128p(P, 512, 512, P, 512, Wio, 512, K, m0, n0, sA, sB, acc);
    EPI
    #pragma unroll
    for (int i = 0; i < 4; ++i) {
        const int row = m0 + wq_r + i * 16 + l4;
        const int b = row >> 8, mm = row & 255;
        #pragma unroll
        for (int j = 0; j < 4; ++j) {
            const int col = n0 + wq_c + j * 16 + lr;
            const int dir = col >> 11, eh = col & 2047;
            const float bia = (dir ? b_out : b_in)[eh];
            const int e = eh >> 9, hh = eh & 511;
            ushort4 w4;
            w4.x = f2h(acc[i][j][0] + bia);
            w4.y = f2h(acc[i][j][1] + bia);
            w4.z = f2h(acc[i][j][2] + bia);
            w4.w = f2h(acc[i][j][3] + bia);
            *reinterpret_cast<ushort4*>(&T[(size_t)dir * TDIR + (size_t)b * 512 * 1024
                                           + (size_t)hh * 1024 + e * 256 + mm]) = w4;
        }
    }
}

// adjacency: per (b,dir): C[256x512] = A16[b][:, dir*1024:+1024] @ T[dir][b]^T
__global__ __launch_bounds__(256, 4) void k_amat(const u16* __restrict__ A16,
                                                 const u16* __restrict__ T,
                                                 u16* __restrict__ acat)
{
    __shared__ u16 sA[2 * 4096], sB[2 * 4096];
    const int fid = xcd_swz(blockIdx.x, gridDim.x);
    const int n = fid & 3, m = (fid >> 2) & 1, bd = fid >> 3;
    const int b = bd >> 1, dir = bd & 1;
    const int m0 = m << 7, n0 = n << 7;
    const u16* A1 = A16 + (size_t)b * 256 * 2048 + dir * 1024;
    const u16* Bt = T + (size_t)dir * TDIR + (size_t)b * 512 * 1024;
    f32x4 acc[4][4] = {};
    gemm128p(A1, 2048, 1024, A1, 2048, Bt, 1024, 1024, m0, n0, sA, sB, acc);
    EPI
    #pragma unroll
    for (int i = 0; i < 4; ++i) {
        const int row = m0 + wq_r + i * 16 + l4;
        #pragma unroll
        for (int j = 0; j < 4; ++j) {
            const int col = n0 + wq_c + j * 16 + lr;
            #pragma unroll
            for (int v = 0; v < 4; ++v)
                acat[((size_t)b * 256 + row + v) * 1024 + dir * 512 + col] = f2h(acc[i][j][v]);
        }
    }
}

// gates: X[8192 x 1536] = [acat | P] @ Wrzh^T (h-block zero-padded over P rows).
// K-trims: h-blocks (n0>=1024) K=1024; step 0 r/z blocks Krz=1280 (P cols 256-511 zero).
__global__ __launch_bounds__(256, 4) void k_gates(const u16* __restrict__ acat,
                                                  const u16* __restrict__ P,
                                                  const u16* __restrict__ Wrzh,
                                                  const float* __restrict__ br,
                                                  const float* __restrict__ bz,
                                                  u16* __restrict__ rp,
                                                  u16* __restrict__ z16,
                                                  u16* __restrict__ hp16,
                                                  int Krz)
{
    __shared__ u16 sA[2 * 4096], sB[2 * 4096];
    const int fid = xcd_swz(blockIdx.x, gridDim.x);
    const int n = fid % 12, m = fid / 12;
    const int m0 = m << 7, n0 = n << 7;
    const int K = (n0 >= 1024) ? 1024 : Krz;
    f32x4 acc[4][4] = {};
    gemm128p(acat, 1024, 1024, P, 512, Wrzh, 1536, K, m0, n0, sA, sB, acc);
    EPI
    #pragma unroll
    for (int i = 0; i < 4; ++i) {
        const int row = m0 + wq_r + i * 16 + l4;
        #pragma unroll
        for (int j = 0; j < 4; ++j) {
            const int col = n0 + wq_c + j * 16 + lr;
            if (col < 512) {
                const float bia = br[col];
                #pragma unroll
                for (int v = 0; v < 4; ++v) {
                    const float s = 1.0f / (1.0f + __expf(-(acc[i][j][v] + bia)));
                    const size_t idx = (size_t)(row + v) * 512 + col;
                    rp[idx] = f2h(s * h2f(P[idx]));
                }
            } else if (col < 1024) {
                const float bia = bz[col - 512];
                #pragma unroll
                for (int v = 0; v < 4; ++v)
                    z16[(size_t)(row + v) * 512 + (col - 512)] =
                        f2h(1.0f / (1.0f + __expf(-(acc[i][j][v] + bia))));
            } else {
                #pragma unroll
                for (int v = 0; v < 4; ++v)
                    hp16[(size_t)(row + v) * 512 + (col - 1024)] = f2h(acc[i][j][v]);
            }
        }
    }
}

// h/update: Y = rp @ WhP^T ; h = tanh(hp + Y + bh) ; P = (1-z)P + z h
// 128x64 tiles. K=256 at step 0 (rp cols 256-511 zero).
__global__ __launch_bounds__(256, 4) void k_hup(const u16* __restrict__ rp,
                                                const u16* __restrict__ WhP,
                                                const float* __restrict__ bh,
                                                const u16* __restrict__ z16,
                                                const u16* __restrict__ hp16,
                                                u16* __restrict__ P, int K)
{
    __shared__ u16 sA[2 * 4096], sB[2 * 2048];
    const int fid = xcd_swz(blockIdx.x, gridDim.x);
    const int n = fid & 7, m = fid >> 3;
    const int m0 = m << 7, n0 = n << 6;
    f32x4 acc[2][4] = {};
    gemm128p64(rp, 512, 512, rp, 512, WhP, 512, K, m0, n0, sA, sB, acc);
    EPI64
    #pragma unroll
    for (int i = 0; i < 2; ++i) {
        const int row = m0 + wq_r + i * 16 + l4;
        #pragma unroll
        for (int j = 0; j < 4; ++j) {
            const int col = n0 + j * 16 + lr;
            const float bia = bh[col];
            #pragma unroll
            for (int v = 0; v < 4; ++v) {
                const size_t idx = (size_t)(row + v) * 512 + col;
                const float hh = tanhf(h2f(hp16[idx]) + acc[i][j][v] + bia);
                const float zz = h2f(z16[idx]);
                const float pn = (1.0f - zz) * h2f(P[idx]) + zz * hh;
                P[idx] = f2h(pn);
            }
        }
    }
}

// final: out = tanh([P | ann] @ Wj^T + bo) (f32), 128x64 tiles, grid 512
__global__ __launch_bounds__(256, 4) void k_final(const u16* __restrict__ P,
                                                  const u16* __restrict__ annf,
                                                  const u16* __restrict__ Wj,
                                                  const float* __restrict__ bo,
                                                  float* __restrict__ out)
{
    __shared__ u16 sA[2 * 4096], sB[2 * 2048];
    const int fid = xcd_swz(blockIdx.x, gridDim.x);
    const int n = fid & 7, m = fid >> 3;
    const int m0 = m << 7, n0 = n << 6;
    f32x4 acc[2][4] = {};
    gemm128p64(P, 512, 512, annf, 256, Wj, 768, 768, m0, n0, sA, sB, acc);
    EPI64
    #pragma unroll
    for (int i = 0; i < 2; ++i) {
        const int row = m0 + wq_r + i * 16 + l4;
        #pragma unroll
        for (int j = 0; j < 4; ++j) {
            const int col = n0 + j * 16 + lr;
            const float bia = bo[col];
            #pragma unroll
            for (int v = 0; v < 4; ++v)
                out[(size_t)(row + v) * 512 + col] = tanhf(acc[i][j][v] + bia);
        }
    }
}

// ---- fused setup: block-segmented. Blocks [0,16384): gather; [16384,24576):
// A f32->f16; [24576, 24576+1248): LDS-tiled 64x64 weight transposes ----
#define BGATH 16384
#define BCVTA 8192
#define TT_WIO  512
#define TT_WR   192
#define TT_WZ   192
#define TT_WH   128
#define TT_Z0   64
#define TT_WHP  64
#define TT_WJ   96
// total tiles = 1248 ; grid = 16384 + 8192 + 1248 = 25824
__global__ void s_setup(const int* __restrict__ ann, const float* __restrict__ emb,
                        const float* __restrict__ A,
                        const float* __restrict__ Wi, const float* __restrict__ Wo,
                        const float* __restrict__ Wr, const float* __restrict__ Wz,
                        const float* __restrict__ Wh, const float* __restrict__ Wj,
                        u16* __restrict__ P, u16* __restrict__ annf,
                        u16* __restrict__ A16,
                        u16* __restrict__ dWio, u16* __restrict__ dWrzh,
                        u16* __restrict__ dWhP, u16* __restrict__ dWj)
{
    const int bid = blockIdx.x, tid = threadIdx.x;
    if (bid < BGATH) {
        const int gid = bid * 256 + tid;             // < 8192*512
        const int row = gid >> 9, d = gid & 511;
        float v = 0.0f;
        if (d < 256) v = emb[(size_t)ann[row] * 256 + d];
        const u16 h = f2h(v);
        P[gid] = h;
        if (d < 256) annf[((size_t)row << 8) + d] = h;
        return;
    }
    if (bid < BGATH + BCVTA) {
        const size_t base = ((size_t)(bid - BGATH) * 256 + tid) * 8;   // < 8192*2048
        float4 f0 = *reinterpret_cast<const float4*>(A + base);
        float4 f1 = *reinterpret_cast<const float4*>(A + base + 4);
        ushort4 p0 = { f2h(f0.x), f2h(f0.y), f2h(f0.z), f2h(f0.w) };
        ushort4 p1 = { f2h(f1.x), f2h(f1.y), f2h(f1.z), f2h(f1.w) };
        *reinterpret_cast<ushort4*>(A16 + base)     = p0;
        *reinterpret_cast<ushort4*>(A16 + base + 4) = p1;
        return;
    }
    // ---- transpose tiles ----
    int tt = bid - (BGATH + BCVTA);
    const float* src = nullptr;       // [*][512] row-major
    u16* dst = nullptr;               // dst[n0+i][k0+j] = src[k0+j][n0+i]
    int ldk = 0, n0 = 0, k0 = 0;
    bool zero = false;
    if (tt < TT_WIO) {
        const int sub = tt >> 6, rem = tt & 63;
        const int dir = sub >> 2, e = sub & 3;
        src = (dir ? Wo : Wi) + (size_t)e * 262144;
        dst = dWio + (size_t)(dir * 2048 + e * 512) * 512;
        ldk = 512; n0 = ((rem >> 3) & 7) << 6; k0 = (rem & 7) << 6;
    } else if ((tt -= TT_WIO) < TT_WR) {
        src = Wr; dst = dWrzh; ldk = 1536;
        n0 = (tt / 24) << 6; k0 = (tt % 24) << 6;
    } else if ((tt -= TT_WR) < TT_WZ) {
        src = Wz; dst = dWrzh + 512 * 1536; ldk = 1536;
        n0 = (tt / 24) << 6; k0 = (tt % 24) << 6;
    } else if ((tt -= TT_WZ) < TT_WH) {
        src = Wh; dst = dWrzh + 1024 * 1536; ldk = 1536;
        n0 = (tt >> 4) << 6; k0 = (tt & 15) << 6;        // k < 1024
    } else if ((tt -= TT_WH) < TT_Z0) {
        dst = dWrzh + 1024 * 1536; ldk = 1536;
        n0 = (tt >> 3) << 6; k0 = 1024 + ((tt & 7) << 6);
        zero = true;
    } else if ((tt -= TT_Z0) < TT_WHP) {
        src = Wh + 1024 * 512; dst = dWhP; ldk = 512;
        n0 = (tt >> 3) << 6; k0 = (tt & 7) << 6;
    } else {
        tt -= TT_WHP;                                    // < TT_WJ
        src = Wj; dst = dWj; ldk = 768;
        n0 = (tt / 12) << 6; k0 = (tt % 12) << 6;
    }

    if (zero) {
        const int jj4 = (tid & 15) << 2;
        #pragma unroll
        for (int p = 0; p < 4; ++p) {
            const int i = (tid >> 4) + p * 16;
            ushort4 zz = { 0, 0, 0, 0 };
            *reinterpret_cast<ushort4*>(&dst[(size_t)(n0 + i) * ldk + k0 + jj4]) = zz;
        }
        return;
    }

    __shared__ float lds[64][65];                        // +1 pad
    {
        const int jj = tid >> 4, i4 = (tid & 15) << 2;
        #pragma unroll
        for (int p = 0; p < 4; ++p) {
            const int j = jj + p * 16;
            float4 f = *reinterpret_cast<const float4*>(src + (size_t)(k0 + j) * 512 + n0 + i4);
            lds[j][i4] = f.x; lds[j][i4 + 1] = f.y; lds[j][i4 + 2] = f.z; lds[j][i4 + 3] = f.w;
        }
    }
    __syncthreads();
    {
        const int j4 = (tid & 15) << 2;
        #pragma unroll
        for (int p = 0; p < 4; ++p) {
            const int i = (tid >> 4) + p * 16;
            ushort4 w;
            w.x = f2h(lds[j4][i]);
            w.y = f2h(lds[j4 + 1][i]);
            w.z = f2h(lds[j4 + 2][i]);
            w.w = f2h(lds[j4 + 3][i]);
            *reinterpret_cast<ushort4*>(&dst[(size_t)(n0 + i) * ldk + k0 + j4]) = w;
        }
    }
}

extern "C" void kernel_launch(void* const* d_in, const int* in_sizes, int n_in,
                              void* d_out, int out_size, void* d_ws, size_t ws_size,
                              hipStream_t stream) {
    const int*   ann   = (const int*)d_in[0];
    const float* A     = (const float*)d_in[1];
    const float* emb   = (const float*)d_in[2];
    const float* W_in  = (const float*)d_in[3];
    const float* b_in  = (const float*)d_in[4];
    const float* W_out = (const float*)d_in[5];
    const float* b_out = (const float*)d_in[6];
    const float* Wr    = (const float*)d_in[7];
    const float* br    = (const float*)d_in[8];
    const float* Wz    = (const float*)d_in[9];
    const float* bz    = (const float*)d_in[10];
    const float* Wh    = (const float*)d_in[11];
    const float* bh    = (const float*)d_in[12];
    const float* Wo    = (const float*)d_in[13];
    const float* bo    = (const float*)d_in[14];
    float* out = (float*)d_out;

    char* ws = (char*)d_ws;
    size_t off = 0;
    auto alloc = [&](size_t bytes) -> void* {
        void* p = ws + off;
        off = (off + bytes + 255) & ~(size_t)255;
        return p;
    };
    u16* z16   = (u16*)alloc(8192ull * 512 * 2);       // 8 MB
    u16* hp16  = (u16*)alloc(8192ull * 512 * 2);       // 8 MB
    u16* P     = (u16*)alloc(8192ull * 512 * 2);       // 8 MB
    u16* rp    = (u16*)alloc(8192ull * 512 * 2);       // 8 MB
    u16* annf  = (u16*)alloc(8192ull * 256 * 2);       // 4 MB
    u16* acat  = (u16*)alloc(8192ull * 1024 * 2);      // 16 MB
    u16* A16   = (u16*)alloc(8192ull * 2048 * 2);      // 32 MB
    u16* T     = (u16*)alloc(2 * TDIR * 2);            // 64 MB
    u16* WioT  = (u16*)alloc(4096ull * 512 * 2);       // 4 MB
    u16* WrzhT = (u16*)alloc(1536ull * 1536 * 2);      // 4.7 MB
    u16* WhPT  = (u16*)alloc(512ull * 512 * 2);        // 0.5 MB
    u16* WjT   = (u16*)alloc(512ull * 768 * 2);        // 0.8 MB
    // total ~158 MB

    s_setup<<<25824, 256, 0, stream>>>(ann, emb, A, W_in, W_out, Wr, Wz, Wh, Wo,
                                       P, annf, A16, WioT, WrzhT, WhPT, WjT);

    for (int s = 0; s < 5; ++s) {
        k_proj<<<2048, 256, 0, stream>>>(P, WioT, b_in, b_out, T, s == 0 ? 256 : 512);
        k_amat<<<512, 256, 0, stream>>>(A16, T, acat);
        k_gates<<<768, 256, 0, stream>>>(acat, P, WrzhT, br, bz, rp, z16, hp16,
                                         s == 0 ? 1280 : 1536);
        k_hup<<<512, 256, 0, stream>>>(rp, WhPT, bh, z16, hp16, P, s == 0 ? 256 : 512);
    }
    k_final<<<512, 256, 0, stream>>>(P, annf, WjT, bo, out);
}